// Round 1
// baseline (11.664 us; speedup 1.0000x reference)
//
#include <hip/hip_runtime.h>

#define T 2048
#define BLK 256
#define K 4

// One block per batch row.
// scores[t] = sum_{i,j} C[i][j] * [x[T-1-i] == x[t-j]]  (t-j>=0), scores[T-1]=-1e9
// attn = softmax(scores); out[v] = sum_{t: x[t]==v} attn[t]
__global__ __launch_bounds__(BLK) void constrained_attn_kernel(
    const int* __restrict__ x, const float* __restrict__ C, float* __restrict__ out)
{
    __shared__ int   xs[T];
    __shared__ float outs[T];
    __shared__ float red[BLK / 64];

    const int b   = blockIdx.x;
    const int tid = threadIdx.x;
    const int* xb = x + b * T;

    for (int t = tid; t < T; t += BLK) {
        xs[t]   = xb[t];
        outs[t] = 0.0f;
    }
    __syncthreads();

    const int q0 = xs[T - 1], q1 = xs[T - 2], q2 = xs[T - 3], q3 = xs[T - 4];
    float c[16];
#pragma unroll
    for (int k = 0; k < 16; ++k) c[k] = C[k];

    float sc[T / BLK];
    float lmax = -1e30f;
#pragma unroll
    for (int r = 0; r < T / BLK; ++r) {
        const int t = tid + r * BLK;
        float s = 0.0f;
#pragma unroll
        for (int j = 0; j < K; ++j) {
            const int tj = t - j;
            if (tj >= 0) {
                const int xv = xs[tj];
                s += (xv == q0 ? c[0 * 4 + j] : 0.0f);
                s += (xv == q1 ? c[1 * 4 + j] : 0.0f);
                s += (xv == q2 ? c[2 * 4 + j] : 0.0f);
                s += (xv == q3 ? c[3 * 4 + j] : 0.0f);
            }
        }
        if (t == T - 1) s = -1e9f;
        sc[r] = s;
        lmax = fmaxf(lmax, s);
    }

    // block-wide max (wave64 butterfly + cross-wave LDS)
#pragma unroll
    for (int off = 32; off > 0; off >>= 1)
        lmax = fmaxf(lmax, __shfl_xor(lmax, off));
    if ((tid & 63) == 0) red[tid >> 6] = lmax;
    __syncthreads();
    float m = red[0];
#pragma unroll
    for (int w = 1; w < BLK / 64; ++w) m = fmaxf(m, red[w]);

    // exp + block-wide sum
    float lsum = 0.0f;
#pragma unroll
    for (int r = 0; r < T / BLK; ++r) {
        sc[r] = __expf(sc[r] - m);
        lsum += sc[r];
    }
#pragma unroll
    for (int off = 32; off > 0; off >>= 1)
        lsum += __shfl_xor(lsum, off);
    __syncthreads();  // red reuse: ensure all reads of max are done
    if ((tid & 63) == 0) red[tid >> 6] = lsum;
    __syncthreads();
    float tot = 0.0f;
#pragma unroll
    for (int w = 0; w < BLK / 64; ++w) tot += red[w];
    const float inv = 1.0f / tot;

    // scatter attn into vocab buckets (LDS atomics; ~1 hit/bucket avg)
#pragma unroll
    for (int r = 0; r < T / BLK; ++r) {
        const int t = tid + r * BLK;
        atomicAdd(&outs[xs[t]], sc[r] * inv);
    }
    __syncthreads();

    float* ob = out + b * T;  // VOCAB == T == 2048
    for (int v = tid; v < T; v += BLK)
        ob[v] = outs[v];
}

extern "C" void kernel_launch(void* const* d_in, const int* in_sizes, int n_in,
                              void* d_out, int out_size, void* d_ws, size_t ws_size,
                              hipStream_t stream) {
    const int*   x = (const int*)d_in[0];
    const float* C = (const float*)d_in[1];
    float*     out = (float*)d_out;
    const int B = in_sizes[0] / T;  // 8
    constrained_attn_kernel<<<B, BLK, 0, stream>>>(x, C, out);
}

// Round 2
// 10.649 us; speedup vs baseline: 1.0953x; 1.0953x over previous
//
#include <hip/hip_runtime.h>

#define T   2048
#define BLK 256
#define PT  (T / BLK)   // 8 positions per thread

// scores[t] = sum_{i,j} C[i][j] * [x[T-1-i] == x[t-j]]  (t-j>=0), scores[T-1]=-1e9
// attn = softmax(scores); out[v] = sum_{t: x[t]==v} attn[t]
//
// One block per batch. Thread tid owns positions [8*tid, 8*tid+8).
// No LDS staging of x: each thread loads its 8 tokens + 3 predecessors +
// the 4 query tokens as int4 (all independent -> one HBM/L2 round trip).
__global__ __launch_bounds__(BLK) void constrained_attn_kernel(
    const int* __restrict__ x, const float* __restrict__ C, float* __restrict__ out)
{
    __shared__ float outs[T];   // per-vocab scatter accumulator (VOCAB == T)
    __shared__ float red[8];    // [0..3] wave maxes, [4..7] wave sums

    const int b    = blockIdx.x;
    const int tid  = threadIdx.x;
    const int* xb  = x + b * T;
    const int base = tid * PT;

    // ---- issue every global load up front (independent, one round trip) ----
    const int4 q4 = *(const int4*)(xb + T - 4);   // {x[T-4],x[T-3],x[T-2],x[T-1]}
    const int4 v0 = *(const int4*)(xb + base);
    const int4 v1 = *(const int4*)(xb + base + 4);
    int4 vp = make_int4(-1, -1, -1, -1);          // -1 sentinel: never matches vocab
    if (tid > 0) vp = *(const int4*)(xb + base - 4);
    const float4 c0 = *(const float4*)(C + 0);
    const float4 c1 = *(const float4*)(C + 4);
    const float4 c2 = *(const float4*)(C + 8);
    const float4 c3 = *(const float4*)(C + 12);

    // zero the scatter accumulator (ordering vs scatter covered by sync #1)
    for (int v = tid; v < T; v += BLK) outs[v] = 0.0f;

    const int q0 = q4.w, q1 = q4.z, q2 = q4.y, q3 = q4.x;  // q_i = x[T-1-i]
    const float c[16] = {c0.x, c0.y, c0.z, c0.w,
                         c1.x, c1.y, c1.z, c1.w,
                         c2.x, c2.y, c2.z, c2.w,
                         c3.x, c3.y, c3.z, c3.w};
    // arr[i] = x[base - 3 + i]  (i = 0..10), static-indexed after unroll
    const int arr[PT + 3] = {vp.y, vp.z, vp.w,
                             v0.x, v0.y, v0.z, v0.w,
                             v1.x, v1.y, v1.z, v1.w};

    float sc[PT];
    float lmax = -1e30f;
#pragma unroll
    for (int k = 0; k < PT; ++k) {
        float s = 0.0f;
#pragma unroll
        for (int j = 0; j < 4; ++j) {
            const int xv = arr[3 + k - j];       // x[t-j]; sentinel -1 if t-j<0
            s += (xv == q0 ? c[0  + j] : 0.0f);
            s += (xv == q1 ? c[4  + j] : 0.0f);
            s += (xv == q2 ? c[8  + j] : 0.0f);
            s += (xv == q3 ? c[12 + j] : 0.0f);
        }
        if (base + k == T - 1) s = -1e9f;
        sc[k] = s;
        lmax = fmaxf(lmax, s);
    }

    // ---- block max: wave64 butterfly + cross-wave LDS ----
#pragma unroll
    for (int off = 32; off > 0; off >>= 1)
        lmax = fmaxf(lmax, __shfl_xor(lmax, off));
    if ((tid & 63) == 0) red[tid >> 6] = lmax;
    __syncthreads();                              // sync #1 (also orders outs zeroing)
    const float m = fmaxf(fmaxf(red[0], red[1]), fmaxf(red[2], red[3]));

    // ---- exp + block sum (separate red slots -> no extra barrier) ----
    float lsum = 0.0f;
#pragma unroll
    for (int k = 0; k < PT; ++k) {
        sc[k] = __expf(sc[k] - m);
        lsum += sc[k];
    }
#pragma unroll
    for (int off = 32; off > 0; off >>= 1)
        lsum += __shfl_xor(lsum, off);
    if ((tid & 63) == 0) red[4 + (tid >> 6)] = lsum;
    __syncthreads();                              // sync #2
    const float inv = 1.0f / (red[4] + red[5] + red[6] + red[7]);

    // ---- scatter attn into vocab buckets ----
#pragma unroll
    for (int k = 0; k < PT; ++k)
        atomicAdd(&outs[arr[3 + k]], sc[k] * inv);
    __syncthreads();                              // sync #3

    // ---- write full output row (covers 0xAA poison) ----
    float* ob = out + b * T;
    *(float4*)(ob + base)     = *(const float4*)(outs + base);
    *(float4*)(ob + base + 4) = *(const float4*)(outs + base + 4);
}

extern "C" void kernel_launch(void* const* d_in, const int* in_sizes, int n_in,
                              void* d_out, int out_size, void* d_ws, size_t ws_size,
                              hipStream_t stream) {
    const int*   x = (const int*)d_in[0];
    const float* C = (const float*)d_in[1];
    float*     out = (float*)d_out;
    const int B = in_sizes[0] / T;  // 8
    constrained_attn_kernel<<<B, BLK, 0, stream>>>(x, C, out);
}